// Round 17
// baseline (579.907 us; speedup 1.0000x reference)
//
#include <hip/hip_runtime.h>
#include <hip/hip_bf16.h>
#include <math.h>

#define NND 20000
#define NED 320000
#define DD  256
#define DEE 128

typedef __attribute__((ext_vector_type(8))) short bf16x8;
typedef __attribute__((ext_vector_type(4))) float f32x4;

__device__ __forceinline__ float b2f(unsigned short u) {
    union { float f; unsigned int i; } x; x.i = ((unsigned int)u) << 16; return x.f;
}
__device__ __forceinline__ unsigned short f2b(float f) {
    union { float f; unsigned int i; } x; x.f = f;
    unsigned int r = x.i + 0x7fffu + ((x.i >> 16) & 1u);
    return (unsigned short)(r >> 16);
}
__device__ __forceinline__ float sigf(float x) { return 1.0f / (1.0f + expf(-x)); }

__device__ __forceinline__ void gload_lds16(const void* g, void* l) {
    __builtin_amdgcn_global_load_lds((const __attribute__((address_space(1))) void*)g,
                                     (__attribute__((address_space(3))) void*)l, 16, 0, 0);
}

// ---------------------------------------------------------------------------
// bf16 MFMA GEMM, 1024 threads = 16 waves (4x4), tile 128x256, wave tile
// 32x64 -> acc[2][4] = 32 regs; __launch_bounds__(1024,8) -> 32 waves/CU.
// Grid: x = n-tiles (N/256), y = m-tiles (A-tile L2 reuse).
// EPI 0: f32 out + bias; EPI 1: bf16 out no bias; EPI 3: bf16 out + bias.
// ---------------------------------------------------------------------------
template<int EPI>
__global__ __launch_bounds__(1024, 8)
void mgemm(const unsigned short* __restrict__ A, int lda,
           const unsigned short* __restrict__ W,
           const float* __restrict__ bias,
           void* __restrict__ Cv, int M, int N, int K) {
    __shared__ unsigned short As[128 * 32];   // 8 KB
    __shared__ unsigned short Bs[256 * 32];   // 16 KB
    const int m0 = blockIdx.y * 128;
    const int n0 = blockIdx.x * 256;
    const int tid = threadIdx.x;
    const int wid = tid >> 6, lane = tid & 63;
    const int wr = wid >> 2, wc = wid & 3;    // 4 x 4 wave grid
    const int srB = tid >> 2;                 // 0..255
    const int sc = (tid & 3) * 8;

    int raA = m0 + (tid >> 2); if (raA >= M) raA = M - 1;   // used by tid<512
    const int rbB = n0 + srB;

    char* lA = (char*)As + wid * 1024;        // waves 0..7
    char* lB = (char*)Bs + wid * 1024;        // all 16 waves

    f32x4 acc[2][4] = {};
    for (int k0 = 0; k0 < K; k0 += 32) {
        __syncthreads();
        if (tid < 512) gload_lds16(A + (size_t)raA * lda + k0 + sc, lA);
        gload_lds16(W + (size_t)rbB * K + k0 + sc, lB);
        __syncthreads();

        bf16x8 af[2], bfr[4];
        const int ar = wr * 32 + (lane & 15);
        const int br = wc * 64 + (lane & 15);
        const int ke = (lane >> 4) * 8;
        #pragma unroll
        for (int m = 0; m < 2; ++m) af[m] = *(const bf16x8*)&As[(ar + m * 16) * 32 + ke];
        #pragma unroll
        for (int n = 0; n < 4; ++n) bfr[n] = *(const bf16x8*)&Bs[(br + n * 16) * 32 + ke];
        #pragma unroll
        for (int m = 0; m < 2; ++m)
            #pragma unroll
            for (int n = 0; n < 4; ++n)
                acc[m][n] = __builtin_amdgcn_mfma_f32_16x16x32_bf16(af[m], bfr[n], acc[m][n], 0, 0, 0);
    }

    const int r0 = m0 + wr * 32 + (lane >> 4) * 4;
    const int c0 = n0 + wc * 64 + (lane & 15);
    #pragma unroll
    for (int n = 0; n < 4; ++n) {
        const int col = c0 + n * 16;
        const float bv = (EPI != 1) ? bias[col] : 0.f;
        #pragma unroll
        for (int m = 0; m < 2; ++m) {
            #pragma unroll
            for (int j = 0; j < 4; ++j) {
                const int row = r0 + m * 16 + j;
                if (row < M) {
                    if (EPI == 0) {
                        ((float*)Cv)[(size_t)row * N + col] = acc[m][n][j] + bv;
                    } else if (EPI == 1) {
                        ((unsigned short*)Cv)[(size_t)row * N + col] = f2b(acc[m][n][j]);
                    } else {
                        ((unsigned short*)Cv)[(size_t)row * N + col] = f2b(acc[m][n][j] + bv);
                    }
                }
            }
        }
    }
}

// ---------------------------------------------------------------------------
// fe2 GEMM with fused f32->bf16 A staging (reads s directly, no cast pass).
// ---------------------------------------------------------------------------
__global__ __launch_bounds__(1024, 8)
void gemm_f2(const float* __restrict__ S,
             const unsigned short* __restrict__ W,
             const float* __restrict__ b2,
             unsigned short* __restrict__ habOut,
             const int* __restrict__ deg, int M) {
    __shared__ unsigned short As[128 * 32];   // 8 KB
    __shared__ unsigned short Bs[256 * 32];   // 16 KB
    const int m0 = blockIdx.y * 128;
    const int tid = threadIdx.x;
    const int wid = tid >> 6, lane = tid & 63;
    const int wr = wid >> 2, wc = wid & 3;
    const int srB = tid >> 2;
    const int sc = (tid & 3) * 8;

    int raA = m0 + (tid >> 2); if (raA >= M) raA = M - 1;

    char* lB = (char*)Bs + wid * 1024;

    f32x4 acc[2][4] = {};
    for (int k0 = 0; k0 < 256; k0 += 32) {
        __syncthreads();
        if (tid < 512) {
            const float4 a0 = *(const float4*)(S + (size_t)raA * 256 + k0 + sc);
            const float4 a1 = *(const float4*)(S + (size_t)raA * 256 + k0 + sc + 4);
            uint4 u;
            u.x = (unsigned int)f2b(a0.x) | ((unsigned int)f2b(a0.y) << 16);
            u.y = (unsigned int)f2b(a0.z) | ((unsigned int)f2b(a0.w) << 16);
            u.z = (unsigned int)f2b(a1.x) | ((unsigned int)f2b(a1.y) << 16);
            u.w = (unsigned int)f2b(a1.z) | ((unsigned int)f2b(a1.w) << 16);
            *(uint4*)&As[(size_t)(tid >> 2) * 32 + sc] = u;
        }
        gload_lds16(W + (size_t)srB * 256 + k0 + sc, lB);
        __syncthreads();

        bf16x8 af[2], bfr[4];
        const int ar = wr * 32 + (lane & 15);
        const int br = wc * 64 + (lane & 15);
        const int ke = (lane >> 4) * 8;
        #pragma unroll
        for (int m = 0; m < 2; ++m) af[m] = *(const bf16x8*)&As[(ar + m * 16) * 32 + ke];
        #pragma unroll
        for (int n = 0; n < 4; ++n) bfr[n] = *(const bf16x8*)&Bs[(br + n * 16) * 32 + ke];
        #pragma unroll
        for (int m = 0; m < 2; ++m)
            #pragma unroll
            for (int n = 0; n < 4; ++n)
                acc[m][n] = __builtin_amdgcn_mfma_f32_16x16x32_bf16(af[m], bfr[n], acc[m][n], 0, 0, 0);
    }

    const int r0 = m0 + wr * 32 + (lane >> 4) * 4;
    const int c0 = wc * 64 + (lane & 15);
    #pragma unroll
    for (int n = 0; n < 4; ++n) {
        const int col = c0 + n * 16;
        const float bv = b2[col];
        #pragma unroll
        for (int m = 0; m < 2; ++m) {
            #pragma unroll
            for (int j = 0; j < 4; ++j) {
                const int row = r0 + m * 16 + j;
                if (row < M) {
                    const float v = acc[m][n][j] + (float)deg[row] * bv;
                    habOut[(size_t)row * 512 + 256 + col] = f2b(v);
                }
            }
        }
    }
}

// ---------------------------------------------------------------------------
// Fused edge message + segment reduce (unchanged from R14/R15 structure).
// ---------------------------------------------------------------------------
__global__ __launch_bounds__(1024, 8)
void edge_fused(const unsigned short* __restrict__ EAB,
                const unsigned short* __restrict__ W,
                const float* __restrict__ b1,
                const unsigned short* __restrict__ UV,
                const int* __restrict__ srcS, const int* __restrict__ dstS,
                float* __restrict__ s) {
    __shared__ union {
        struct { unsigned short As[4096]; unsigned short Bs[16384]; } g;
        unsigned short T[128 * 260];
    } sm;
    __shared__ int dloc[128];
    __shared__ int sloc[128];
    __shared__ int segs[130];
    __shared__ unsigned long long smask[2];
    __shared__ int nseg;

    // bijective XCD swizzle: nwg=2500, q=312, r=4
    const int orig = blockIdx.x;
    const int xcd = orig & 7;
    const int j = orig >> 3;
    const int wgid = (xcd < 4 ? xcd * 313 : 4 * 313 + (xcd - 4) * 312) + j;
    const int e0 = wgid * 128;

    const int tid = threadIdx.x;
    const int wid = tid >> 6, lane = tid & 63;
    const int wr = wid >> 2, wc = wid & 3;       // 4 x 4 wave grid
    const int srB = tid >> 2;                    // 0..255 (B rows)
    const int sc = (tid & 3) * 8;

    if (tid >= 256 && tid < 384) dloc[tid - 256] = dstS[e0 + tid - 256];
    else if (tid >= 384 && tid < 512) sloc[tid - 384] = srcS[e0 + tid - 384];

    char* lA = (char*)sm.g.As + wid * 1024;      // waves 0..7 only
    char* lB = (char*)sm.g.Bs + wid * 1024;      // all 16 waves

    f32x4 acc[2][4] = {};
    for (int k0 = 0; k0 < DEE; k0 += 32) {
        __syncthreads();
        if (tid < 512) gload_lds16(EAB + (size_t)(e0 + (tid >> 2)) * DEE + k0 + sc, lA);
        gload_lds16(W + (size_t)srB * DEE + k0 + sc, lB);
        __syncthreads();

        bf16x8 af[2], bfr[4];
        const int ar = wr * 32 + (lane & 15);
        const int br = wc * 64 + (lane & 15);
        const int ke = (lane >> 4) * 8;
        #pragma unroll
        for (int m = 0; m < 2; ++m) af[m] = *(const bf16x8*)&sm.g.As[(ar + m * 16) * 32 + ke];
        #pragma unroll
        for (int n = 0; n < 4; ++n) bfr[n] = *(const bf16x8*)&sm.g.Bs[(br + n * 16) * 32 + ke];
        #pragma unroll
        for (int m = 0; m < 2; ++m)
            #pragma unroll
            for (int n = 0; n < 4; ++n)
                acc[m][n] = __builtin_amdgcn_mfma_f32_16x16x32_bf16(af[m], bfr[n], acc[m][n], 0, 0, 0);
    }
    __syncthreads();   // staging reads done before T overwrites As/Bs

    // Phase 1 epilogue: raw acc -> T
    {
        const int lr0 = wr * 32 + (lane >> 4) * 4;
        const int lc0 = wc * 64 + (lane & 15);
        #pragma unroll
        for (int m = 0; m < 2; ++m)
            #pragma unroll
            for (int j2 = 0; j2 < 4; ++j2)
                #pragma unroll
                for (int n = 0; n < 4; ++n)
                    sm.T[(lr0 + m * 16 + j2) * 260 + lc0 + n * 16] = f2b(acc[m][n][j2]);
    }
    __syncthreads();

    const int cp = (tid & 127) * 2;              // col-pair base
    const int rg = tid >> 7;                     // row group 0..7

    // Phase 2: T += V[src]  (u32 pairs, inline gather, independent iters)
    #pragma unroll 4
    for (int rr = 0; rr < 16; ++rr) {
        const int r = rr * 8 + rg;
        const unsigned int v2 = *(const unsigned int*)&UV[(size_t)sloc[r] * 512 + 256 + cp];
        unsigned int* tp = (unsigned int*)&sm.T[r * 260 + cp];
        const unsigned int t2 = *tp;
        const float t0 = b2f((unsigned short)(t2 & 0xffffu)) + b2f((unsigned short)(v2 & 0xffffu));
        const float t1 = b2f((unsigned short)(t2 >> 16)) + b2f((unsigned short)(v2 >> 16));
        *tp = (unsigned int)f2b(t0) | ((unsigned int)f2b(t1) << 16);
    }

    // segment boundaries from sorted dst (waves 0,1 only)
    if (tid < 128) {
        const int b = (tid == 0) || (dloc[tid] != dloc[tid - 1]);
        const unsigned long long mk = __ballot(b);
        if ((tid & 63) == 0) smask[tid >> 6] = mk;
    }
    __syncthreads();
    if (tid == 0) {
        int k = 0;
        #pragma unroll
        for (int w2 = 0; w2 < 2; ++w2) {
            unsigned long long m = smask[w2];
            while (m) {
                const int b2_ = __ffsll((long long)m) - 1;
                segs[k++] = w2 * 64 + b2_;
                m &= m - 1;
            }
        }
        segs[k] = 128;
        nseg = k;
    }
    __syncthreads();

    // Phase 3: 8-way parallel per-segment relu-sum (LDS pairs; U once/seg)
    {
        const int ns = nseg;
        const float b1v0 = b1[cp], b1v1 = b1[cp + 1];
        for (int g2 = rg; g2 < ns; g2 += 8) {
            const int lo = segs[g2], hi = segs[g2 + 1];
            const int node = dloc[lo];
            const unsigned int u2 = *(const unsigned int*)&UV[(size_t)node * 512 + cp];
            const float u0 = b2f((unsigned short)(u2 & 0xffffu)) + b1v0;
            const float u1 = b2f((unsigned short)(u2 >> 16)) + b1v1;
            float a0 = 0.f, a1 = 0.f;
            for (int r = lo; r < hi; ++r) {
                const unsigned int t2 = *(const unsigned int*)&sm.T[r * 260 + cp];
                a0 += fmaxf(b2f((unsigned short)(t2 & 0xffffu)) + u0, 0.f);
                a1 += fmaxf(b2f((unsigned short)(t2 >> 16)) + u1, 0.f);
            }
            float* dp = s + (size_t)node * 256 + cp;
            if (g2 == 0 || g2 == ns - 1) {
                atomicAdd(dp, a0);
                atomicAdd(dp + 1, a1);
            } else {
                dp[0] = a0;
                dp[1] = a1;
            }
        }
    }
}

// ---------------------------------------------------------------------------
// gates GEMM (K=512, N=1024 gate-interleaved weights) + fused LSTM cell.
// ---------------------------------------------------------------------------
__global__ __launch_bounds__(1024, 8)
void gemm_lstm(const unsigned short* __restrict__ Ain,
               const unsigned short* __restrict__ W,
               const float* __restrict__ pb,
               float* __restrict__ c, unsigned short* __restrict__ habOut, int M) {
    __shared__ unsigned short As[128 * 32];   // 8 KB
    __shared__ unsigned short Bs[256 * 32];   // 16 KB
    const int m0 = blockIdx.y * 128;
    const int n0 = blockIdx.x * 256;
    const int tid = threadIdx.x;
    const int wid = tid >> 6, lane = tid & 63;
    const int wr = wid >> 2, wc = wid & 3;    // 4 x 4 wave grid
    const int srB = tid >> 2;                 // 0..255
    const int sc = (tid & 3) * 8;

    int raA = m0 + (tid >> 2); if (raA >= M) raA = M - 1;   // used by tid<512
    const int rbB = n0 + srB;

    char* lA = (char*)As + wid * 1024;        // waves 0..7
    char* lB = (char*)Bs + wid * 1024;        // all 16 waves

    f32x4 acc[2][4] = {};
    for (int k0 = 0; k0 < 512; k0 += 32) {
        __syncthreads();
        if (tid < 512) gload_lds16(Ain + (size_t)raA * 512 + k0 + sc, lA);
        gload_lds16(W + (size_t)rbB * 512 + k0 + sc, lB);
        __syncthreads();

        bf16x8 af[2], bfr[4];
        const int ar = wr * 32 + (lane & 15);
        const int br = wc * 64 + (lane & 15);
        const int ke = (lane >> 4) * 8;
        #pragma unroll
        for (int m = 0; m < 2; ++m) af[m] = *(const bf16x8*)&As[(ar + m * 16) * 32 + ke];
        #pragma unroll
        for (int n = 0; n < 4; ++n) bfr[n] = *(const bf16x8*)&Bs[(br + n * 16) * 32 + ke];
        #pragma unroll
        for (int m = 0; m < 2; ++m)
            #pragma unroll
            for (int n = 0; n < 4; ++n)
                acc[m][n] = __builtin_amdgcn_mfma_f32_16x16x32_bf16(af[m], bfr[n], acc[m][n], 0, 0, 0);
    }

    const int r0 = m0 + wr * 32 + (lane >> 4) * 4;
    const int c0 = n0 + wc * 64 + (lane & 15);
    const int dim = ((c0 >> 6) << 4) | (lane & 15);
    float pbv[4];
    #pragma unroll
    for (int n = 0; n < 4; ++n) pbv[n] = pb[c0 + n * 16];
    #pragma unroll
    for (int m = 0; m < 2; ++m) {
        #pragma unroll
        for (int j = 0; j < 4; ++j) {
            const int v = r0 + m * 16 + j;
            if (v < M) {
                const float gi = acc[m][0][j] + pbv[0];
                const float gf = acc[m][1][j] + pbv[1];
                const float gg = acc[m][2][j] + pbv[2];
                const float go = acc[m][3][j] + pbv[3];
                const float cold = c[(size_t)v * 256 + dim];
                const float nc = sigf(gf) * cold + sigf(gi) * tanhf(gg);
                const float nh = sigf(go) * tanhf(nc);
                c[(size_t)v * 256 + dim] = nc;
                habOut[(size_t)v * 512 + dim] = f2b(nh);
            }
        }
    }
}

// ---------------------------------------------------------------------------
// Merged independent setup: count_deg | cast x->hab | cast_weights | prep_bias
// Blocks: [0,1250) count_deg, [1250,6250) cast x, [6250,7850) weights,
// [7850,7860) bias. All branches independent of each other.
// ---------------------------------------------------------------------------
__global__ __launch_bounds__(256)
void setup_misc(const int* __restrict__ dst, int* __restrict__ deg,
                const float* __restrict__ x, unsigned short* __restrict__ hab,
                const float* __restrict__ fe1, const float* __restrict__ fe2,
                const float* __restrict__ wih, const float* __restrict__ whh,
                const float* __restrict__ gmw, const float* __restrict__ fmw,
                unsigned short* __restrict__ wb,
                const float* __restrict__ b_ih, const float* __restrict__ b_hh,
                const float* __restrict__ gm_b, const float* __restrict__ fm_b,
                float* __restrict__ pb, float* __restrict__ gfb) {
    const int b = blockIdx.x;
    const int tid = threadIdx.x;
    if (b < 1250) {
        const int e = b * 256 + tid;
        if (e < NED) atomicAdd(&deg[dst[e]], 1);
    } else if (b < 6250) {
        const long g = ((long)(b - 1250) * 256 + tid) * 4;
        if (g < (long)NND * 256) {
            const int r = (int)(g >> 8), cc = (int)(g & 255);
            const float4 v = *(const float4*)(x + (size_t)r * 256 + cc);
            unsigned short* d = hab + (size_t)r * 512 + cc;
            d[0] = f2b(v.x); d[1] = f2b(v.y); d[2] = f2b(v.z); d[3] = f2b(v.w);
        }
    } else if (b < 7850) {
        const long o = ((long)(b - 6250) * 256 + tid) * 4;
        if (o < 1638400L) {
            const float* srcp;
            if (o < 262144L) {                       // WUV: [i][512][256]
                const int i = (int)(o >> 17); const int w = (int)(o & 131071);
                const int r = w >> 8, col = w & 255;
                srcp = fe1 + (size_t)i * 163840 + (r < 256 ? (size_t)r * 640 + col
                                                           : (size_t)(r - 256) * 640 + 256 + col);
            } else if (o < 327680L) {                // WEB: [i][256][128]
                const long w = o - 262144L;
                const int i = (int)(w >> 15); const int ww = (int)(w & 32767);
                srcp = fe1 + (size_t)i * 163840 + (size_t)(ww >> 7) * 640 + 512 + (ww & 127);
            } else if (o < 458752L) {                // WF2: [i][256][256]
                const long w = o - 327680L;
                const int i = (int)(w >> 16); const int ww = (int)(w & 65535);
                srcp = fe2 + (size_t)i * 65536 + ww;
            } else if (o < 1507328L) {               // WG: gate-interleaved
                const long w = o - 458752L;
                const int i = (int)(w >> 19); const int ww = (int)(w & 524287);
                const int rp = ww >> 9, k = ww & 511;
                const int gate = (rp >> 4) & 3;
                const int dim = ((rp >> 6) << 4) | (rp & 15);
                const int orig = gate * 256 + dim;
                srcp = (k < 256) ? wih + (size_t)i * 262144 + (size_t)orig * 256 + k
                                 : whh + (size_t)i * 262144 + (size_t)orig * 256 + (k - 256);
            } else {                                 // WGM: [512][256]
                const long w = o - 1507328L;
                const int r = (int)(w >> 8), col = (int)(w & 255);
                srcp = (r < 256) ? gmw + (size_t)r * 256 + col
                                 : fmw + (size_t)(r - 256) * 256 + col;
            }
            const float4 v = *(const float4*)srcp;
            wb[o] = f2b(v.x); wb[o + 1] = f2b(v.y); wb[o + 2] = f2b(v.z); wb[o + 3] = f2b(v.w);
        }
    } else {
        const int t = (b - 7850) * 256 + tid;
        if (t < 2048) {
            const int i = t >> 10, cth = t & 1023;
            const int gate = (cth >> 4) & 3;
            const int dim = ((cth >> 6) << 4) | (cth & 15);
            const int orig = gate * 256 + dim;
            pb[t] = b_ih[i * 1024 + orig] + b_hh[i * 1024 + orig];
        } else if (t < 2304) gfb[t - 2048] = gm_b[t - 2048];
        else if (t < 2560) gfb[t - 2048] = fm_b[t - 2304];
    }
}

__global__ __launch_bounds__(256)
void gcvt(const float* __restrict__ EA, const int* __restrict__ perm,
          unsigned short* __restrict__ EB) {
    const int g = blockIdx.x * 256 + threadIdx.x;
    if (g >= NED * 32) return;
    const int r = g >> 5, j = (g & 31) * 4;
    const int e = perm[r];
    const float4 v = *(const float4*)(EA + (size_t)e * DEE + j);
    unsigned short* d = EB + (size_t)r * DEE + j;
    d[0] = f2b(v.x); d[1] = f2b(v.y); d[2] = f2b(v.z); d[3] = f2b(v.w);
}

__global__ __launch_bounds__(1024)
void scan_offsets(const int* __restrict__ deg, int* __restrict__ off,
                  int* __restrict__ cursor) {
    __shared__ int wpre[16];
    __shared__ int stot;
    const int t = threadIdx.x, wid = t >> 6, lane = t & 63;
    int carry = 0;
    for (int base = 0; base < 20480; base += 1024) {
        const int idx = base + t;
        const int val = (idx < NND) ? deg[idx] : 0;
        int x = val;
        #pragma unroll
        for (int d = 1; d < 64; d <<= 1) {
            const int y = __shfl_up(x, d, 64);
            if (lane >= d) x += y;
        }
        if (lane == 63) wpre[wid] = x;
        __syncthreads();
        if (wid == 0 && lane < 16) {
            const int w = wpre[lane];
            int xx = w;
            #pragma unroll
            for (int d = 1; d < 16; d <<= 1) {
                const int y = __shfl_up(xx, d, 16);
                if (lane >= d) xx += y;
            }
            wpre[lane] = xx - w;
            if (lane == 15) stot = xx;
        }
        __syncthreads();
        const int ex = carry + wpre[wid] + x - val;
        if (idx < NND) { off[idx] = ex; cursor[idx] = ex; }
        carry += stot;
        __syncthreads();
    }
    if (t == 0) off[NND] = carry;
}

__global__ __launch_bounds__(256)
void scatter_edges(const int* __restrict__ dst, const int* __restrict__ src,
                   int* __restrict__ cursor, int* __restrict__ perm,
                   int* __restrict__ srcS, int* __restrict__ dstS) {
    const int e = blockIdx.x * 256 + threadIdx.x;
    if (e < NED) {
        const int d = dst[e];
        const int p = atomicAdd(&cursor[d], 1);
        perm[p] = e;
        srcS[p] = src[e];
        dstS[p] = d;
    }
}

// out[g] += sum_v sigmoid(RO[v,g]) * RO[v,256+g]   (RO bf16; 1024 thr, 8 rgrp)
__global__ __launch_bounds__(1024)
void readout_reduce(const unsigned short* __restrict__ RO, float* __restrict__ out) {
    const int tid = threadIdx.x;
    const int cp = (tid & 127) * 2;
    const int rg = tid >> 7;                 // 0..7
    const int v0 = blockIdx.x * 128;
    float a0 = 0.f, a1 = 0.f;
    for (int r = rg; r < 128; r += 8) {
        const int v = v0 + r;
        if (v >= NND) break;
        const unsigned int g2 = *(const unsigned int*)&RO[(size_t)v * 512 + cp];
        const unsigned int h2 = *(const unsigned int*)&RO[(size_t)v * 512 + 256 + cp];
        a0 += sigf(b2f((unsigned short)(g2 & 0xffffu))) * b2f((unsigned short)(h2 & 0xffffu));
        a1 += sigf(b2f((unsigned short)(g2 >> 16))) * b2f((unsigned short)(h2 >> 16));
    }
    atomicAdd(&out[cp], a0);
    atomicAdd(&out[cp + 1], a1);
}

extern "C" void kernel_launch(void* const* d_in, const int* in_sizes, int n_in,
                              void* d_out, int out_size, void* d_ws, size_t ws_size,
                              hipStream_t stream) {
    const float* x         = (const float*)d_in[0];
    const float* edge_attr = (const float*)d_in[1];
    const int*   eidx      = (const int*)d_in[2];
    const float* fe1_W     = (const float*)d_in[3];
    const float* fe1_b     = (const float*)d_in[4];
    const float* fe2_W     = (const float*)d_in[5];
    const float* fe2_b     = (const float*)d_in[6];
    const float* W_ih      = (const float*)d_in[7];
    const float* W_hh      = (const float*)d_in[8];
    const float* b_ih      = (const float*)d_in[9];
    const float* b_hh      = (const float*)d_in[10];
    const float* gm_W      = (const float*)d_in[11];
    const float* gm_b      = (const float*)d_in[12];
    const float* fm_W      = (const float*)d_in[13];
    const float* fm_b      = (const float*)d_in[14];
    float* out = (float*)d_out;

    const int* src = eidx;
    const int* dst = eidx + NED;

    // ---- workspace layout (float offsets) ---------------------------------
    float* ws = (float*)d_ws;
    unsigned short* UVb  = (unsigned short*)ws;
    unsigned short* ROb  = (unsigned short*)ws;            // readout reuses UV region
    float*          s    = ws + 5120000L;
    float*          c    = ws + 12800000L;
    unsigned short* habA = (unsigned short*)(ws + 17920000L);
    unsigned short* wb   = (unsigned short*)(ws + 23040000L);
    float*          pb   = ws + 23860000L;
    float*          gfb  = ws + 23862048L;
    int*            ib   = (int*)(ws + 23870000L);
    int* deg    = ib;                 // 20000
    int* off    = ib + 20000;         // 20001
    int* cursor = ib + 40001;         // 20000
    int* perm   = ib + 60002;         // 320000
    int* srcS   = ib + 380002;        // 320000
    int* dstS   = ib + 700002;        // 320000 -> ends 1020002
    unsigned short* EABs = (unsigned short*)(ws + 24900000L);
    unsigned short* habB = (unsigned short*)(ws + 45380000L);

    // weight table offsets (bf16 elements)
    const long WUV = 0;        // [i]: 512x256  (+i*131072)
    const long WEB = 262144;   // [i]: 256x128  (+i*32768)
    const long WF2 = 327680;   // [i]: 256x256  (+i*65536)
    const long WG  = 458752;   // [i]: 1024x512 (+i*524288) gate-interleaved
    const long WGM = 1507328;  // 512x256

    // ---- setup -------------------------------------------------------------
    hipMemsetAsync(c, 0, (size_t)NND * DD * 4, stream);
    hipMemsetAsync(deg, 0, (size_t)NND * 4, stream);
    setup_misc<<<7860, 256, 0, stream>>>(dst, deg, x, habA,
                                         fe1_W, fe2_W, W_ih, W_hh, gm_W, fm_W, wb,
                                         b_ih, b_hh, gm_b, fm_b, pb, gfb);
    scan_offsets<<<1, 1024, 0, stream>>>(deg, off, cursor);
    scatter_edges<<<(NED + 255) / 256, 256, 0, stream>>>(dst, src, cursor, perm, srcS, dstS);
    gcvt<<<40000, 256, 0, stream>>>(edge_attr, perm, EABs);

    // n-tiles on x (few), m-tiles on y (157) -> A reuse across consecutive blocks
    const dim3 gUV(2, 157), gF2(1, 157), gGT(4, 157), gRO(2, 157);

    unsigned short* habC = habA;
    unsigned short* habN = habB;
    for (int i = 0; i < 2; ++i) {
        mgemm<1><<<gUV, 1024, 0, stream>>>(habC, 512, wb + WUV + i * 131072,
                                           nullptr, UVb, NND, 512, 256);
        hipMemsetAsync(s, 0, (size_t)NND * DD * 4, stream);
        edge_fused<<<2500, 1024, 0, stream>>>(EABs, wb + WEB + i * 32768,
                                              fe1_b + (size_t)i * 256, UVb, srcS, dstS, s);
        gemm_f2<<<gF2, 1024, 0, stream>>>(s, wb + WF2 + i * 65536,
                                          fe2_b + (size_t)i * 256, habC, deg, NND);
        gemm_lstm<<<gGT, 1024, 0, stream>>>(habC, wb + WG + i * 524288,
                                            pb + (size_t)i * 1024, c, habN, NND);
        unsigned short* tmp = habC; habC = habN; habN = tmp;
    }

    mgemm<3><<<gRO, 1024, 0, stream>>>(habC, 512, wb + WGM, gfb, ROb, NND, 512, 256);
    hipMemsetAsync(out, 0, 256 * 4, stream);
    readout_reduce<<<157, 1024, 0, stream>>>(ROb, out);
}

// Round 18
// 517.322 us; speedup vs baseline: 1.1210x; 1.1210x over previous
//
#include <hip/hip_runtime.h>
#include <hip/hip_bf16.h>
#include <math.h>

#define NND 20000
#define NED 320000
#define DD  256
#define DEE 128

typedef __attribute__((ext_vector_type(8))) short bf16x8;
typedef __attribute__((ext_vector_type(4))) float f32x4;

__device__ __forceinline__ float b2f(unsigned short u) {
    union { float f; unsigned int i; } x; x.i = ((unsigned int)u) << 16; return x.f;
}
__device__ __forceinline__ unsigned short f2b(float f) {
    union { float f; unsigned int i; } x; x.f = f;
    unsigned int r = x.i + 0x7fffu + ((x.i >> 16) & 1u);
    return (unsigned short)(r >> 16);
}
__device__ __forceinline__ float sigf(float x) { return 1.0f / (1.0f + expf(-x)); }

__device__ __forceinline__ void gload_lds16(const void* g, void* l) {
    __builtin_amdgcn_global_load_lds((const __attribute__((address_space(1))) void*)g,
                                     (__attribute__((address_space(3))) void*)l, 16, 0, 0);
}

// ---------------------------------------------------------------------------
// bf16 MFMA GEMM, 1024 threads = 16 waves (4x4), tile 128x256, wave tile
// 32x64 -> acc[2][4] = 32 regs; __launch_bounds__(1024,8) -> 32 waves/CU.
// Grid: x = n-tiles (N/256), y = m-tiles (A-tile L2 reuse).
// EPI 0: f32 out + bias; EPI 1: bf16 out no bias; EPI 3: bf16 out + bias.
// ---------------------------------------------------------------------------
template<int EPI>
__global__ __launch_bounds__(1024, 8)
void mgemm(const unsigned short* __restrict__ A, int lda,
           const unsigned short* __restrict__ W,
           const float* __restrict__ bias,
           void* __restrict__ Cv, int M, int N, int K) {
    __shared__ unsigned short As[128 * 32];   // 8 KB
    __shared__ unsigned short Bs[256 * 32];   // 16 KB
    const int m0 = blockIdx.y * 128;
    const int n0 = blockIdx.x * 256;
    const int tid = threadIdx.x;
    const int wid = tid >> 6, lane = tid & 63;
    const int wr = wid >> 2, wc = wid & 3;    // 4 x 4 wave grid
    const int srB = tid >> 2;                 // 0..255
    const int sc = (tid & 3) * 8;

    int raA = m0 + (tid >> 2); if (raA >= M) raA = M - 1;   // used by tid<512
    const int rbB = n0 + srB;

    char* lA = (char*)As + wid * 1024;        // waves 0..7
    char* lB = (char*)Bs + wid * 1024;        // all 16 waves

    f32x4 acc[2][4] = {};
    for (int k0 = 0; k0 < K; k0 += 32) {
        __syncthreads();
        if (tid < 512) gload_lds16(A + (size_t)raA * lda + k0 + sc, lA);
        gload_lds16(W + (size_t)rbB * K + k0 + sc, lB);
        __syncthreads();

        bf16x8 af[2], bfr[4];
        const int ar = wr * 32 + (lane & 15);
        const int br = wc * 64 + (lane & 15);
        const int ke = (lane >> 4) * 8;
        #pragma unroll
        for (int m = 0; m < 2; ++m) af[m] = *(const bf16x8*)&As[(ar + m * 16) * 32 + ke];
        #pragma unroll
        for (int n = 0; n < 4; ++n) bfr[n] = *(const bf16x8*)&Bs[(br + n * 16) * 32 + ke];
        #pragma unroll
        for (int m = 0; m < 2; ++m)
            #pragma unroll
            for (int n = 0; n < 4; ++n)
                acc[m][n] = __builtin_amdgcn_mfma_f32_16x16x32_bf16(af[m], bfr[n], acc[m][n], 0, 0, 0);
    }

    const int r0 = m0 + wr * 32 + (lane >> 4) * 4;
    const int c0 = n0 + wc * 64 + (lane & 15);
    #pragma unroll
    for (int n = 0; n < 4; ++n) {
        const int col = c0 + n * 16;
        const float bv = (EPI != 1) ? bias[col] : 0.f;
        #pragma unroll
        for (int m = 0; m < 2; ++m) {
            #pragma unroll
            for (int j = 0; j < 4; ++j) {
                const int row = r0 + m * 16 + j;
                if (row < M) {
                    if (EPI == 0) {
                        ((float*)Cv)[(size_t)row * N + col] = acc[m][n][j] + bv;
                    } else if (EPI == 1) {
                        ((unsigned short*)Cv)[(size_t)row * N + col] = f2b(acc[m][n][j]);
                    } else {
                        ((unsigned short*)Cv)[(size_t)row * N + col] = f2b(acc[m][n][j] + bv);
                    }
                }
            }
        }
    }
}

// ---------------------------------------------------------------------------
// fe2 GEMM with fused f32->bf16 A staging (reads s directly, no cast pass).
// ---------------------------------------------------------------------------
__global__ __launch_bounds__(1024, 8)
void gemm_f2(const float* __restrict__ S,
             const unsigned short* __restrict__ W,
             const float* __restrict__ b2,
             unsigned short* __restrict__ habOut,
             const int* __restrict__ deg, int M) {
    __shared__ unsigned short As[128 * 32];   // 8 KB
    __shared__ unsigned short Bs[256 * 32];   // 16 KB
    const int m0 = blockIdx.y * 128;
    const int tid = threadIdx.x;
    const int wid = tid >> 6, lane = tid & 63;
    const int wr = wid >> 2, wc = wid & 3;
    const int srB = tid >> 2;
    const int sc = (tid & 3) * 8;

    int raA = m0 + (tid >> 2); if (raA >= M) raA = M - 1;

    char* lB = (char*)Bs + wid * 1024;

    f32x4 acc[2][4] = {};
    for (int k0 = 0; k0 < 256; k0 += 32) {
        __syncthreads();
        if (tid < 512) {
            const float4 a0 = *(const float4*)(S + (size_t)raA * 256 + k0 + sc);
            const float4 a1 = *(const float4*)(S + (size_t)raA * 256 + k0 + sc + 4);
            uint4 u;
            u.x = (unsigned int)f2b(a0.x) | ((unsigned int)f2b(a0.y) << 16);
            u.y = (unsigned int)f2b(a0.z) | ((unsigned int)f2b(a0.w) << 16);
            u.z = (unsigned int)f2b(a1.x) | ((unsigned int)f2b(a1.y) << 16);
            u.w = (unsigned int)f2b(a1.z) | ((unsigned int)f2b(a1.w) << 16);
            *(uint4*)&As[(size_t)(tid >> 2) * 32 + sc] = u;
        }
        gload_lds16(W + (size_t)srB * 256 + k0 + sc, lB);
        __syncthreads();

        bf16x8 af[2], bfr[4];
        const int ar = wr * 32 + (lane & 15);
        const int br = wc * 64 + (lane & 15);
        const int ke = (lane >> 4) * 8;
        #pragma unroll
        for (int m = 0; m < 2; ++m) af[m] = *(const bf16x8*)&As[(ar + m * 16) * 32 + ke];
        #pragma unroll
        for (int n = 0; n < 4; ++n) bfr[n] = *(const bf16x8*)&Bs[(br + n * 16) * 32 + ke];
        #pragma unroll
        for (int m = 0; m < 2; ++m)
            #pragma unroll
            for (int n = 0; n < 4; ++n)
                acc[m][n] = __builtin_amdgcn_mfma_f32_16x16x32_bf16(af[m], bfr[n], acc[m][n], 0, 0, 0);
    }

    const int r0 = m0 + wr * 32 + (lane >> 4) * 4;
    const int c0 = wc * 64 + (lane & 15);
    #pragma unroll
    for (int n = 0; n < 4; ++n) {
        const int col = c0 + n * 16;
        const float bv = b2[col];
        #pragma unroll
        for (int m = 0; m < 2; ++m) {
            #pragma unroll
            for (int j = 0; j < 4; ++j) {
                const int row = r0 + m * 16 + j;
                if (row < M) {
                    const float v = acc[m][n][j] + (float)deg[row] * bv;
                    habOut[(size_t)row * 512 + 256 + col] = f2b(v);
                }
            }
        }
    }
}

// ---------------------------------------------------------------------------
// Fused edge message + segment reduce (R14/R15 structure).
// ---------------------------------------------------------------------------
__global__ __launch_bounds__(1024, 8)
void edge_fused(const unsigned short* __restrict__ EAB,
                const unsigned short* __restrict__ W,
                const float* __restrict__ b1,
                const unsigned short* __restrict__ UV,
                const int* __restrict__ srcS, const int* __restrict__ dstS,
                float* __restrict__ s) {
    __shared__ union {
        struct { unsigned short As[4096]; unsigned short Bs[16384]; } g;
        unsigned short T[128 * 260];
    } sm;
    __shared__ int dloc[128];
    __shared__ int sloc[128];
    __shared__ int segs[130];
    __shared__ unsigned long long smask[2];
    __shared__ int nseg;

    // bijective XCD swizzle: nwg=2500, q=312, r=4
    const int orig = blockIdx.x;
    const int xcd = orig & 7;
    const int j = orig >> 3;
    const int wgid = (xcd < 4 ? xcd * 313 : 4 * 313 + (xcd - 4) * 312) + j;
    const int e0 = wgid * 128;

    const int tid = threadIdx.x;
    const int wid = tid >> 6, lane = tid & 63;
    const int wr = wid >> 2, wc = wid & 3;       // 4 x 4 wave grid
    const int srB = tid >> 2;                    // 0..255 (B rows)
    const int sc = (tid & 3) * 8;

    if (tid >= 256 && tid < 384) dloc[tid - 256] = dstS[e0 + tid - 256];
    else if (tid >= 384 && tid < 512) sloc[tid - 384] = srcS[e0 + tid - 384];

    char* lA = (char*)sm.g.As + wid * 1024;      // waves 0..7 only
    char* lB = (char*)sm.g.Bs + wid * 1024;      // all 16 waves

    f32x4 acc[2][4] = {};
    for (int k0 = 0; k0 < DEE; k0 += 32) {
        __syncthreads();
        if (tid < 512) gload_lds16(EAB + (size_t)(e0 + (tid >> 2)) * DEE + k0 + sc, lA);
        gload_lds16(W + (size_t)srB * DEE + k0 + sc, lB);
        __syncthreads();

        bf16x8 af[2], bfr[4];
        const int ar = wr * 32 + (lane & 15);
        const int br = wc * 64 + (lane & 15);
        const int ke = (lane >> 4) * 8;
        #pragma unroll
        for (int m = 0; m < 2; ++m) af[m] = *(const bf16x8*)&sm.g.As[(ar + m * 16) * 32 + ke];
        #pragma unroll
        for (int n = 0; n < 4; ++n) bfr[n] = *(const bf16x8*)&sm.g.Bs[(br + n * 16) * 32 + ke];
        #pragma unroll
        for (int m = 0; m < 2; ++m)
            #pragma unroll
            for (int n = 0; n < 4; ++n)
                acc[m][n] = __builtin_amdgcn_mfma_f32_16x16x32_bf16(af[m], bfr[n], acc[m][n], 0, 0, 0);
    }
    __syncthreads();   // staging reads done before T overwrites As/Bs

    // Phase 1 epilogue: raw acc -> T
    {
        const int lr0 = wr * 32 + (lane >> 4) * 4;
        const int lc0 = wc * 64 + (lane & 15);
        #pragma unroll
        for (int m = 0; m < 2; ++m)
            #pragma unroll
            for (int j2 = 0; j2 < 4; ++j2)
                #pragma unroll
                for (int n = 0; n < 4; ++n)
                    sm.T[(lr0 + m * 16 + j2) * 260 + lc0 + n * 16] = f2b(acc[m][n][j2]);
    }
    __syncthreads();

    const int cp = (tid & 127) * 2;              // col-pair base
    const int rg = tid >> 7;                     // row group 0..7

    // Phase 2: T += V[src]  (u32 pairs, inline gather, independent iters)
    #pragma unroll 4
    for (int rr = 0; rr < 16; ++rr) {
        const int r = rr * 8 + rg;
        const unsigned int v2 = *(const unsigned int*)&UV[(size_t)sloc[r] * 512 + 256 + cp];
        unsigned int* tp = (unsigned int*)&sm.T[r * 260 + cp];
        const unsigned int t2 = *tp;
        const float t0 = b2f((unsigned short)(t2 & 0xffffu)) + b2f((unsigned short)(v2 & 0xffffu));
        const float t1 = b2f((unsigned short)(t2 >> 16)) + b2f((unsigned short)(v2 >> 16));
        *tp = (unsigned int)f2b(t0) | ((unsigned int)f2b(t1) << 16);
    }

    // segment boundaries from sorted dst (waves 0,1 only)
    if (tid < 128) {
        const int b = (tid == 0) || (dloc[tid] != dloc[tid - 1]);
        const unsigned long long mk = __ballot(b);
        if ((tid & 63) == 0) smask[tid >> 6] = mk;
    }
    __syncthreads();
    if (tid == 0) {
        int k = 0;
        #pragma unroll
        for (int w2 = 0; w2 < 2; ++w2) {
            unsigned long long m = smask[w2];
            while (m) {
                const int b2_ = __ffsll((long long)m) - 1;
                segs[k++] = w2 * 64 + b2_;
                m &= m - 1;
            }
        }
        segs[k] = 128;
        nseg = k;
    }
    __syncthreads();

    // Phase 3: 8-way parallel per-segment relu-sum (LDS pairs; U once/seg)
    {
        const int ns = nseg;
        const float b1v0 = b1[cp], b1v1 = b1[cp + 1];
        for (int g2 = rg; g2 < ns; g2 += 8) {
            const int lo = segs[g2], hi = segs[g2 + 1];
            const int node = dloc[lo];
            const unsigned int u2 = *(const unsigned int*)&UV[(size_t)node * 512 + cp];
            const float u0 = b2f((unsigned short)(u2 & 0xffffu)) + b1v0;
            const float u1 = b2f((unsigned short)(u2 >> 16)) + b1v1;
            float a0 = 0.f, a1 = 0.f;
            for (int r = lo; r < hi; ++r) {
                const unsigned int t2 = *(const unsigned int*)&sm.T[r * 260 + cp];
                a0 += fmaxf(b2f((unsigned short)(t2 & 0xffffu)) + u0, 0.f);
                a1 += fmaxf(b2f((unsigned short)(t2 >> 16)) + u1, 0.f);
            }
            float* dp = s + (size_t)node * 256 + cp;
            if (g2 == 0 || g2 == ns - 1) {
                atomicAdd(dp, a0);
                atomicAdd(dp + 1, a1);
            } else {
                dp[0] = a0;
                dp[1] = a1;
            }
        }
    }
}

// ---------------------------------------------------------------------------
// gates GEMM (K=512, N=1024 gate-interleaved weights) + fused LSTM cell.
// ---------------------------------------------------------------------------
__global__ __launch_bounds__(1024, 8)
void gemm_lstm(const unsigned short* __restrict__ Ain,
               const unsigned short* __restrict__ W,
               const float* __restrict__ pb,
               float* __restrict__ c, unsigned short* __restrict__ habOut, int M) {
    __shared__ unsigned short As[128 * 32];   // 8 KB
    __shared__ unsigned short Bs[256 * 32];   // 16 KB
    const int m0 = blockIdx.y * 128;
    const int n0 = blockIdx.x * 256;
    const int tid = threadIdx.x;
    const int wid = tid >> 6, lane = tid & 63;
    const int wr = wid >> 2, wc = wid & 3;    // 4 x 4 wave grid
    const int srB = tid >> 2;                 // 0..255
    const int sc = (tid & 3) * 8;

    int raA = m0 + (tid >> 2); if (raA >= M) raA = M - 1;   // used by tid<512
    const int rbB = n0 + srB;

    char* lA = (char*)As + wid * 1024;        // waves 0..7
    char* lB = (char*)Bs + wid * 1024;        // all 16 waves

    f32x4 acc[2][4] = {};
    for (int k0 = 0; k0 < 512; k0 += 32) {
        __syncthreads();
        if (tid < 512) gload_lds16(Ain + (size_t)raA * 512 + k0 + sc, lA);
        gload_lds16(W + (size_t)rbB * 512 + k0 + sc, lB);
        __syncthreads();

        bf16x8 af[2], bfr[4];
        const int ar = wr * 32 + (lane & 15);
        const int br = wc * 64 + (lane & 15);
        const int ke = (lane >> 4) * 8;
        #pragma unroll
        for (int m = 0; m < 2; ++m) af[m] = *(const bf16x8*)&As[(ar + m * 16) * 32 + ke];
        #pragma unroll
        for (int n = 0; n < 4; ++n) bfr[n] = *(const bf16x8*)&Bs[(br + n * 16) * 32 + ke];
        #pragma unroll
        for (int m = 0; m < 2; ++m)
            #pragma unroll
            for (int n = 0; n < 4; ++n)
                acc[m][n] = __builtin_amdgcn_mfma_f32_16x16x32_bf16(af[m], bfr[n], acc[m][n], 0, 0, 0);
    }

    const int r0 = m0 + wr * 32 + (lane >> 4) * 4;
    const int c0 = n0 + wc * 64 + (lane & 15);
    const int dim = ((c0 >> 6) << 4) | (lane & 15);
    float pbv[4];
    #pragma unroll
    for (int n = 0; n < 4; ++n) pbv[n] = pb[c0 + n * 16];
    #pragma unroll
    for (int m = 0; m < 2; ++m) {
        #pragma unroll
        for (int j = 0; j < 4; ++j) {
            const int v = r0 + m * 16 + j;
            if (v < M) {
                const float gi = acc[m][0][j] + pbv[0];
                const float gf = acc[m][1][j] + pbv[1];
                const float gg = acc[m][2][j] + pbv[2];
                const float go = acc[m][3][j] + pbv[3];
                const float cold = c[(size_t)v * 256 + dim];
                const float nc = sigf(gf) * cold + sigf(gi) * tanhf(gg);
                const float nh = sigf(go) * tanhf(nc);
                c[(size_t)v * 256 + dim] = nc;
                habOut[(size_t)v * 512 + dim] = f2b(nh);
            }
        }
    }
}

__global__ __launch_bounds__(256)
void cast_blk(const float* __restrict__ src, int lds_, int col0,
              int rows, int cols, unsigned short* __restrict__ dst,
              int ldd, int dr, int dc) {
    const long g = ((long)blockIdx.x * 256 + threadIdx.x) * 4;
    if (g >= (long)rows * cols) return;
    const int r = (int)(g / cols), cc = (int)(g % cols);
    const float4 v = *(const float4*)(src + (size_t)r * lds_ + col0 + cc);
    unsigned short* d = dst + (size_t)(dr + r) * ldd + dc + cc;
    d[0] = f2b(v.x); d[1] = f2b(v.y); d[2] = f2b(v.z); d[3] = f2b(v.w);
}

// all weights -> bf16 table (incl. gate-interleaved WG permutation)
__global__ __launch_bounds__(256)
void cast_weights(const float* __restrict__ fe1, const float* __restrict__ fe2,
                  const float* __restrict__ wih, const float* __restrict__ whh,
                  const float* __restrict__ gmw, const float* __restrict__ fmw,
                  unsigned short* __restrict__ wb) {
    const long o = ((long)blockIdx.x * 256 + threadIdx.x) * 4;
    if (o >= 1638400L) return;
    const float* srcp;
    if (o < 262144L) {                       // WUV: [i][512][256]
        const int i = (int)(o >> 17); const int w = (int)(o & 131071);
        const int r = w >> 8, col = w & 255;
        srcp = fe1 + (size_t)i * 163840 + (r < 256 ? (size_t)r * 640 + col
                                                   : (size_t)(r - 256) * 640 + 256 + col);
    } else if (o < 327680L) {                // WEB: [i][256][128]
        const long w = o - 262144L;
        const int i = (int)(w >> 15); const int ww = (int)(w & 32767);
        srcp = fe1 + (size_t)i * 163840 + (size_t)(ww >> 7) * 640 + 512 + (ww & 127);
    } else if (o < 458752L) {                // WF2: [i][256][256]
        const long w = o - 327680L;
        const int i = (int)(w >> 16); const int ww = (int)(w & 65535);
        srcp = fe2 + (size_t)i * 65536 + ww;
    } else if (o < 1507328L) {               // WG: [i][1024'][512], gate-interleaved
        const long w = o - 458752L;
        const int i = (int)(w >> 19); const int ww = (int)(w & 524287);
        const int rp = ww >> 9, k = ww & 511;
        const int gate = (rp >> 4) & 3;
        const int dim = ((rp >> 6) << 4) | (rp & 15);
        const int orig = gate * 256 + dim;
        srcp = (k < 256) ? wih + (size_t)i * 262144 + (size_t)orig * 256 + k
                         : whh + (size_t)i * 262144 + (size_t)orig * 256 + (k - 256);
    } else {                                 // WGM: [512][256]
        const long w = o - 1507328L;
        const int r = (int)(w >> 8), col = (int)(w & 255);
        srcp = (r < 256) ? gmw + (size_t)r * 256 + col
                         : fmw + (size_t)(r - 256) * 256 + col;
    }
    const float4 v = *(const float4*)srcp;
    wb[o] = f2b(v.x); wb[o + 1] = f2b(v.y); wb[o + 2] = f2b(v.z); wb[o + 3] = f2b(v.w);
}

__global__ __launch_bounds__(256)
void gcvt(const float* __restrict__ EA, const int* __restrict__ perm,
          unsigned short* __restrict__ EB) {
    const int g = blockIdx.x * 256 + threadIdx.x;
    if (g >= NED * 32) return;
    const int r = g >> 5, j = (g & 31) * 4;
    const int e = perm[r];
    const float4 v = *(const float4*)(EA + (size_t)e * DEE + j);
    unsigned short* d = EB + (size_t)r * DEE + j;
    d[0] = f2b(v.x); d[1] = f2b(v.y); d[2] = f2b(v.z); d[3] = f2b(v.w);
}

__global__ __launch_bounds__(256)
void count_deg(const int* __restrict__ dst, int* __restrict__ deg) {
    const int e = blockIdx.x * 256 + threadIdx.x;
    if (e < NED) atomicAdd(&deg[dst[e]], 1);
}

__global__ __launch_bounds__(1024)
void scan_offsets(const int* __restrict__ deg, int* __restrict__ off,
                  int* __restrict__ cursor) {
    __shared__ int wpre[16];
    __shared__ int stot;
    const int t = threadIdx.x, wid = t >> 6, lane = t & 63;
    int carry = 0;
    for (int base = 0; base < 20480; base += 1024) {
        const int idx = base + t;
        const int val = (idx < NND) ? deg[idx] : 0;
        int x = val;
        #pragma unroll
        for (int d = 1; d < 64; d <<= 1) {
            const int y = __shfl_up(x, d, 64);
            if (lane >= d) x += y;
        }
        if (lane == 63) wpre[wid] = x;
        __syncthreads();
        if (wid == 0 && lane < 16) {
            const int w = wpre[lane];
            int xx = w;
            #pragma unroll
            for (int d = 1; d < 16; d <<= 1) {
                const int y = __shfl_up(xx, d, 16);
                if (lane >= d) xx += y;
            }
            wpre[lane] = xx - w;
            if (lane == 15) stot = xx;
        }
        __syncthreads();
        const int ex = carry + wpre[wid] + x - val;
        if (idx < NND) { off[idx] = ex; cursor[idx] = ex; }
        carry += stot;
        __syncthreads();
    }
    if (t == 0) off[NND] = carry;
}

__global__ __launch_bounds__(256)
void scatter_edges(const int* __restrict__ dst, const int* __restrict__ src,
                   int* __restrict__ cursor, int* __restrict__ perm,
                   int* __restrict__ srcS, int* __restrict__ dstS) {
    const int e = blockIdx.x * 256 + threadIdx.x;
    if (e < NED) {
        const int d = dst[e];
        const int p = atomicAdd(&cursor[d], 1);
        perm[p] = e;
        srcS[p] = src[e];
        dstS[p] = d;
    }
}

// pb (gate-interleaved b_ih+b_hh) and gfb (gm_b|fm_b)
__global__ __launch_bounds__(256)
void prep_bias(const float* __restrict__ b_ih, const float* __restrict__ b_hh,
               const float* __restrict__ gm_b, const float* __restrict__ fm_b,
               float* __restrict__ pb, float* __restrict__ gfb) {
    const int t = blockIdx.x * 256 + threadIdx.x;
    if (t < 2048) {
        const int i = t >> 10, cth = t & 1023;
        const int gate = (cth >> 4) & 3;
        const int dim = ((cth >> 6) << 4) | (cth & 15);
        const int orig = gate * 256 + dim;
        pb[t] = b_ih[i * 1024 + orig] + b_hh[i * 1024 + orig];
    } else if (t < 2304) gfb[t - 2048] = gm_b[t - 2048];
    else if (t < 2560) gfb[t - 2048] = fm_b[t - 2304];
}

// out[g] += sum_v sigmoid(RO[v,g]) * RO[v,256+g]   (RO bf16; 1024 thr,
// 8 row-groups, LDS partial reduction -> 256 atomics per block)
__global__ __launch_bounds__(1024)
void readout_reduce(const unsigned short* __restrict__ RO, float* __restrict__ out) {
    __shared__ float part[8][258];
    const int tid = threadIdx.x;
    const int cp = (tid & 127) * 2;
    const int rg = tid >> 7;                 // 0..7
    const int v0 = blockIdx.x * 128;
    float a0 = 0.f, a1 = 0.f;
    for (int r = rg; r < 128; r += 8) {
        const int v = v0 + r;
        if (v >= NND) break;
        const unsigned int g2 = *(const unsigned int*)&RO[(size_t)v * 512 + cp];
        const unsigned int h2 = *(const unsigned int*)&RO[(size_t)v * 512 + 256 + cp];
        a0 += sigf(b2f((unsigned short)(g2 & 0xffffu))) * b2f((unsigned short)(h2 & 0xffffu));
        a1 += sigf(b2f((unsigned short)(g2 >> 16))) * b2f((unsigned short)(h2 >> 16));
    }
    part[rg][cp - (cp >> 7) * 128 + (cp >> 7) * 129] = a0;      // avoid 8-col bank alias
    part[rg][cp + 1 - ((cp + 1) >> 7) * 128 + ((cp + 1) >> 7) * 129] = a1;
    __syncthreads();
    if (tid < 256) {
        const int col = tid;
        const int idx = col - (col >> 7) * 128 + (col >> 7) * 129;
        float acc = 0.f;
        #pragma unroll
        for (int g2 = 0; g2 < 8; ++g2) acc += part[g2][idx];
        atomicAdd(&out[col], acc);
    }
}

extern "C" void kernel_launch(void* const* d_in, const int* in_sizes, int n_in,
                              void* d_out, int out_size, void* d_ws, size_t ws_size,
                              hipStream_t stream) {
    const float* x         = (const float*)d_in[0];
    const float* edge_attr = (const float*)d_in[1];
    const int*   eidx      = (const int*)d_in[2];
    const float* fe1_W     = (const float*)d_in[3];
    const float* fe1_b     = (const float*)d_in[4];
    const float* fe2_W     = (const float*)d_in[5];
    const float* fe2_b     = (const float*)d_in[6];
    const float* W_ih      = (const float*)d_in[7];
    const float* W_hh      = (const float*)d_in[8];
    const float* b_ih      = (const float*)d_in[9];
    const float* b_hh      = (const float*)d_in[10];
    const float* gm_W      = (const float*)d_in[11];
    const float* gm_b      = (const float*)d_in[12];
    const float* fm_W      = (const float*)d_in[13];
    const float* fm_b      = (const float*)d_in[14];
    float* out = (float*)d_out;

    const int* src = eidx;
    const int* dst = eidx + NED;

    // ---- workspace layout (float offsets) ---------------------------------
    float* ws = (float*)d_ws;
    unsigned short* UVb  = (unsigned short*)ws;
    unsigned short* ROb  = (unsigned short*)ws;            // readout reuses UV region
    float*          s    = ws + 5120000L;
    float*          c    = ws + 12800000L;
    unsigned short* habA = (unsigned short*)(ws + 17920000L);
    unsigned short* wb   = (unsigned short*)(ws + 23040000L);
    float*          pb   = ws + 23860000L;
    float*          gfb  = ws + 23862048L;
    int*            ib   = (int*)(ws + 23870000L);
    int* deg    = ib;                 // 20000
    int* off    = ib + 20000;         // 20001
    int* cursor = ib + 40001;         // 20000
    int* perm   = ib + 60002;         // 320000
    int* srcS   = ib + 380002;        // 320000
    int* dstS   = ib + 700002;        // 320000 -> ends 1020002
    unsigned short* EABs = (unsigned short*)(ws + 24900000L);
    unsigned short* habB = (unsigned short*)(ws + 45380000L);

    // weight table offsets (bf16 elements)
    const long WUV = 0;        // [i]: 512x256  (+i*131072)
    const long WEB = 262144;   // [i]: 256x128  (+i*32768)
    const long WF2 = 327680;   // [i]: 256x256  (+i*65536)
    const long WG  = 458752;   // [i]: 1024x512 (+i*524288) gate-interleaved
    const long WGM = 1507328;  // 512x256

    // ---- setup -------------------------------------------------------------
    hipMemsetAsync(c, 0, (size_t)NND * DD * 4, stream);
    hipMemsetAsync(deg, 0, (size_t)NND * 4, stream);
    count_deg<<<(NED + 255) / 256, 256, 0, stream>>>(dst, deg);
    scan_offsets<<<1, 1024, 0, stream>>>(deg, off, cursor);
    scatter_edges<<<(NED + 255) / 256, 256, 0, stream>>>(dst, src, cursor, perm, srcS, dstS);
    prep_bias<<<10, 256, 0, stream>>>(b_ih, b_hh, gm_b, fm_b, pb, gfb);
    cast_blk<<<5000, 256, 0, stream>>>(x, 256, 0, NND, 256, habA, 512, 0, 0);
    gcvt<<<40000, 256, 0, stream>>>(edge_attr, perm, EABs);
    cast_weights<<<1600, 256, 0, stream>>>(fe1_W, fe2_W, W_ih, W_hh, gm_W, fm_W, wb);

    // n-tiles on x (few), m-tiles on y (157) -> A reuse across consecutive blocks
    const dim3 gUV(2, 157), gF2(1, 157), gGT(4, 157), gRO(2, 157);

    unsigned short* habC = habA;
    unsigned short* habN = habB;
    for (int i = 0; i < 2; ++i) {
        mgemm<1><<<gUV, 1024, 0, stream>>>(habC, 512, wb + WUV + i * 131072,
                                           nullptr, UVb, NND, 512, 256);
        hipMemsetAsync(s, 0, (size_t)NND * DD * 4, stream);
        edge_fused<<<2500, 1024, 0, stream>>>(EABs, wb + WEB + i * 32768,
                                              fe1_b + (size_t)i * 256, UVb, srcS, dstS, s);
        gemm_f2<<<gF2, 1024, 0, stream>>>(s, wb + WF2 + i * 65536,
                                          fe2_b + (size_t)i * 256, habC, deg, NND);
        gemm_lstm<<<gGT, 1024, 0, stream>>>(habC, wb + WG + i * 524288,
                                            pb + (size_t)i * 1024, c, habN, NND);
        unsigned short* tmp = habC; habC = habN; habN = tmp;
    }

    mgemm<3><<<gRO, 1024, 0, stream>>>(habC, 512, wb + WGM, gfb, ROb, NND, 512, 256);
    hipMemsetAsync(out, 0, 256 * 4, stream);
    readout_reduce<<<157, 1024, 0, stream>>>(ROb, out);
}